// Round 1
// baseline (157.302 us; speedup 1.0000x reference)
//
#include <hip/hip_runtime.h>
#include <hip/hip_fp16.h>

#define E_     5
#define H_     64
#define N_     64
#define MB_    64
#define N_DET_ 16
#define L_     8
#define DIA_   110
#define V_     (MB_*N_)        // 4096
#define NVOX_  (H_*N_*N_)      // 262144
#define K_     (DIA_*V_)       // 450560

// ---------------------------------------------------------------------------
// Kernel 1: bilinear-rotate grid_concentration, overwrite h==0 slab with xp,
// pack the 5 element values per voxel into fp16 AoS (stride 8 halves = 16 B).
// ---------------------------------------------------------------------------
__global__ __launch_bounds__(256) void k_rot(const float* __restrict__ grid,
                                             const float* __restrict__ xp,
                                             const int* __restrict__ theta_idx,
                                             __half* __restrict__ conc16)
{
    int idx = blockIdx.x * 256 + threadIdx.x;      // voxel index in [0, NVOX)
    int x = idx & 63;
    int y = (idx >> 6) & 63;
    int h = idx >> 12;

    float vals[E_];
    if (h == 0) {
        // conc_rot[:, 0:MB, :] = xp  (P_BLK == 0, m == y)
        #pragma unroll
        for (int e = 0; e < E_; ++e) vals[e] = xp[e * V_ + y * 64 + x];
    } else {
        int ti = theta_idx[0];
        float theta = (float)(-((double)ti * 6.283185307179586 / 200.0));
        float ct = cosf(theta), st = sinf(theta);
        const float c = 31.5f;
        float ys = (float)y - c, xs = (float)x - c;
        float ysrc = ct * ys - st * xs + c;
        float xsrc = st * ys + ct * xs + c;
        float y0 = floorf(ysrc), x0 = floorf(xsrc);
        float wy = ysrc - y0, wx = xsrc - x0;
        float y1 = y0 + 1.0f, x1 = x0 + 1.0f;

        bool by0 = (y0 >= 0.0f) && (y0 <= 63.0f);
        bool by1 = (y1 >= 0.0f) && (y1 <= 63.0f);
        bool bx0 = (x0 >= 0.0f) && (x0 <= 63.0f);
        bool bx1 = (x1 >= 0.0f) && (x1 <= 63.0f);

        int y0c = min(max((int)y0, 0), 63), y1c = min(max((int)y1, 0), 63);
        int x0c = min(max((int)x0, 0), 63), x1c = min(max((int)x1, 0), 63);

        float w00 = (1.0f - wy) * (1.0f - wx) * ((by0 && bx0) ? 1.0f : 0.0f);
        float w01 = (1.0f - wy) * wx          * ((by0 && bx1) ? 1.0f : 0.0f);
        float w10 = wy * (1.0f - wx)          * ((by1 && bx0) ? 1.0f : 0.0f);
        float w11 = wy * wx                   * ((by1 && bx1) ? 1.0f : 0.0f);

        #pragma unroll
        for (int e = 0; e < E_; ++e) {
            const float* base = grid + ((size_t)(e * 64 + h) << 12);
            vals[e] = w00 * base[y0c * 64 + x0c] + w01 * base[y0c * 64 + x1c]
                    + w10 * base[y1c * 64 + x0c] + w11 * base[y1c * 64 + x1c];
        }
    }

    __half hv[8];
    #pragma unroll
    for (int e = 0; e < E_; ++e) hv[e] = __float2half(vals[e]);
    hv[5] = __float2half(0.0f); hv[6] = hv[5]; hv[7] = hv[5];
    float4 pack;
    pack = *(const float4*)hv;
    ((float4*)conc16)[idx] = pack;
}

// ---------------------------------------------------------------------------
// Kernel 2: probe attenuation cumsum (exact fp32) + transmission output.
// One block, 64 threads, thread m handles one beam row.
// ---------------------------------------------------------------------------
__global__ void k_att(const float* __restrict__ xp, const float* __restrict__ pa,
                      float* __restrict__ att_ws, float* __restrict__ out_trans)
{
    int m = threadIdx.x;   // 0..63
    float a0 = pa[0], a1 = pa[1], a2 = pa[2], a3 = pa[3], a4 = pa[4];
    const float scale = 0.01f / 64.0f;   // CM / N
    float s = 0.0f;
    for (int n = 0; n < 64; ++n) {
        int o = m * 64 + n;
        att_ws[o] = expf(-s * scale);    // exp(-acc[:, :-1])  (exclusive cumsum)
        float lac = xp[o] * a0 + xp[V_ + o] * a1 + xp[2 * V_ + o] * a2
                  + xp[3 * V_ + o] * a3 + xp[4 * V_ + o] * a4;
        s += lac;
    }
    out_trans[m] = 1.0e7f * expf(-s * scale);   // PROBE_CTS * transmission
}

// ---------------------------------------------------------------------------
// Kernel 3 (dominant): per (d,v) pair, sum over DIA=110 path segments of
// conc16[P_idx]*P_len (5 element planes via one 16-B gather), wave-reduce,
// apply FL_line_attCS per line l, store exp(-att) into SAexp[d][v][l].
// One wave (64 lanes) per (d,v); 65536 waves total.
// ---------------------------------------------------------------------------
__global__ __launch_bounds__(256) void k_main(const int* __restrict__ P_idx,
                                              const float* __restrict__ P_len,
                                              const float4* __restrict__ conc16,
                                              const float* __restrict__ FL,
                                              float* __restrict__ SAexp)
{
    int lane = threadIdx.x & 63;
    int w = blockIdx.x * 4 + (threadIdx.x >> 6);   // (d,v) pair id, [0, 65536)
    int d = w >> 12;
    int v = w & 4095;
    int l = lane & 7;

    float fll[E_];
    #pragma unroll
    for (int e = 0; e < E_; ++e) fll[e] = FL[e * L_ + l];

    size_t base = (size_t)d * K_ + (size_t)v * DIA_;
    float p0 = 0.f, p1 = 0.f, p2 = 0.f, p3 = 0.f, p4 = 0.f;

    #pragma unroll
    for (int it = 0; it < 2; ++it) {
        int i = lane + it * 64;
        if (i < DIA_) {
            int idx = P_idx[base + i];          // coalesced stream
            float len = P_len[base + i];        // coalesced stream
            float4 q = conc16[idx];             // single-line 16-B gather
            const __half2* h2 = (const __half2*)&q;
            float2 c01 = __half22float2(h2[0]);
            float2 c23 = __half22float2(h2[1]);
            float2 c45 = __half22float2(h2[2]);
            p0 += c01.x * len; p1 += c01.y * len;
            p2 += c23.x * len; p3 += c23.y * len;
            p4 += c45.x * len;
        }
    }

    // butterfly reduce the 5 per-element partial sums across the 64-lane wave
    #pragma unroll
    for (int off = 32; off; off >>= 1) {
        p0 += __shfl_xor(p0, off, 64);
        p1 += __shfl_xor(p1, off, 64);
        p2 += __shfl_xor(p2, off, 64);
        p3 += __shfl_xor(p3, off, 64);
        p4 += __shfl_xor(p4, off, 64);
    }

    float att = p0 * fll[0] + p1 * fll[1] + p2 * fll[2] + p3 * fll[3] + p4 * fll[4];
    float sa = expf(-att);
    if (lane < 8)
        SAexp[(size_t)w * 8 + lane] = sa;   // 32-B contiguous store per wave
}

// ---------------------------------------------------------------------------
// Kernel 4: SA mean over detectors + fluorescence weighting + n-reduction.
// One wave per (l,m) output cell; lane = n.
// ---------------------------------------------------------------------------
__global__ void k_out(const float* __restrict__ SAexp, const float* __restrict__ att_ws,
                      const float* __restrict__ xp, const float* __restrict__ dfl,
                      float* __restrict__ out)
{
    int l = blockIdx.x >> 6;
    int m = blockIdx.x & 63;
    int n = threadIdx.x;           // 0..63
    int v = m * 64 + n;

    float s = 0.0f;
    #pragma unroll
    for (int d = 0; d < N_DET_; ++d)
        s += SAexp[(size_t)((d << 12) + v) * 8 + l];

    int elem = (l < 2) ? l : ((l >> 1) + 1);   // LINE_TO_ELEM = {0,1,2,2,3,3,4,4}
    float wgt = 1.0e7f * att_ws[v] * dfl[l] * xp[elem * V_ + v] * (1.0f / 16.0f);
    float val = wgt * s;

    #pragma unroll
    for (int off = 32; off; off >>= 1) val += __shfl_xor(val, off, 64);
    if (n == 0) out[l * 64 + m] = val;
}

// ---------------------------------------------------------------------------
extern "C" void kernel_launch(void* const* d_in, const int* in_sizes, int n_in,
                              void* d_out, int out_size, void* d_ws, size_t ws_size,
                              hipStream_t stream)
{
    const float* grid  = (const float*)d_in[0];   // (E,H,N,N)
    const float* xp    = (const float*)d_in[1];   // (E,MB,N)
    const float* P_len = (const float*)d_in[2];   // (N_DET,K)
    const float* dfl   = (const float*)d_in[3];   // (L,)
    const float* FL    = (const float*)d_in[4];   // (E,L)
    const float* pa    = (const float*)d_in[5];   // (E,)
    const int*   P_idx = (const int*)d_in[6];     // (N_DET,K)
    const int*   tidx  = (const int*)d_in[7];     // scalar

    float* out = (float*)d_out;                   // [fl_signal(8*64) | trans(64)]

    char* ws = (char*)d_ws;
    __half* conc16 = (__half*)ws;                          // 4 MB (NVOX*16 B)
    float*  att_ws = (float*)(ws + (size_t)NVOX_ * 16);    // 16 KB
    float*  SAexp  = (float*)(ws + (size_t)NVOX_ * 16 + V_ * 4); // 2 MB

    k_rot <<<NVOX_ / 256, 256, 0, stream>>>(grid, xp, tidx, conc16);
    k_att <<<1, 64, 0, stream>>>(xp, pa, att_ws, out + L_ * MB_);
    k_main<<<(N_DET_ * V_) / 4, 256, 0, stream>>>(P_idx, P_len,
                                                  (const float4*)conc16, FL, SAexp);
    k_out <<<L_ * MB_, 64, 0, stream>>>(SAexp, att_ws, xp, dfl, out);
}